// Round 8
// baseline (624.444 us; speedup 1.0000x reference)
//
#include <hip/hip_runtime.h>

// SelfAttention (B=4, C=256, H=W=64): fused projections + merged-wave flash.
// Round 11: r10 FAILED (absmax inf) from a row-indexing bug in the new
// normalized epilogue: acc register e belongs to q-row (e&3)+8*(e>>2)+4h
// (PV D-layout), but invl was indexed by lane (=q-row in the QK layout).
// Wrong-row normalization with fixed-M row sums spanning 1e-6..1e12 -> f16
// overflow. Fix: redistribute 1/l to registers via 16 __shfl (lane -> row).
// All of r10's structure stands: fixed-M exp2 softmax (no max chain), zero
// barriers, zero LDS, split-K x4 (1024 blocks x 4 waves = 16 waves/CU),
// normalized f16 partials + l, exact weighted 4-way combine.

#define B_ 4
#define C_ 256
#define N_ 4096
#define CQK 32
#define LOG2E 1.44269504088896340736f

typedef __attribute__((ext_vector_type(8))) short short8;
typedef __attribute__((ext_vector_type(4))) short short4v;
typedef __attribute__((ext_vector_type(4))) unsigned int uint4v;
typedef __attribute__((ext_vector_type(16))) float f32x16;
typedef __attribute__((ext_vector_type(4))) float f32x4;

__device__ __forceinline__ unsigned short f2bf(float f) {
  unsigned int u = __builtin_bit_cast(unsigned int, f);
  u = (u + 0x7fffu + ((u >> 16) & 1u)) >> 16;  // RNE
  return (unsigned short)u;
}
__device__ __forceinline__ float bf2f(unsigned short s) {
  unsigned int u = ((unsigned int)s) << 16;
  return __builtin_bit_cast(float, u);
}
__device__ __forceinline__ short f32tof16(float f) {
  const _Float16 hf = (_Float16)f;
  return __builtin_bit_cast(short, hf);
}
// pack two f32 -> two bf16 (RNE), one instruction
__device__ __forceinline__ unsigned int cvtpk(float lo, float hi) {
  unsigned int r;
  asm("v_cvt_pk_bf16_f32 %0, %1, %2" : "=v"(r) : "v"(lo), "v"(hi));
  return r;
}
__device__ __forceinline__ f32x16 mfma16(short8 a, short8 b, f32x16 c) {
  return __builtin_amdgcn_mfma_f32_32x32x16_bf16(a, b, c, 0, 0, 0);
}
// swizzled element index into bf16 LDS tiles (16B granules XORed by row)
__device__ __forceinline__ int swz64(int row, int col) {  // rows of 64 bf16
  return row * 64 + ((((col >> 3) ^ row) & 7) << 3) + (col & 7);
}

// ---------------- kernel 1: prep (x transpose+split, weight splits) ----------
__global__ __launch_bounds__(256) void k_prep(
    const float* __restrict__ x, unsigned short* __restrict__ xthi,
    unsigned short* __restrict__ xtlo,
    const float* __restrict__ Wq, const float* __restrict__ Wk,
    const float* __restrict__ Wv,
    unsigned short* __restrict__ wqh, unsigned short* __restrict__ wql,
    unsigned short* __restrict__ wkh, unsigned short* __restrict__ wkl,
    unsigned short* __restrict__ wvh, unsigned short* __restrict__ wvl) {
  __shared__ __align__(16) float tile[64 * 65];
  const int bi = blockIdx.x;
  const int t = threadIdx.x;
  if (bi < 1024) {
    const int it = bi & 63, ct = (bi >> 6) & 3, b = bi >> 8;
    const int i0 = it * 64, c0 = ct * 64;
    {
      const int i = t & 63, cb = t >> 6;
#pragma unroll
      for (int z = 0; z < 16; ++z) {
        const int c = z * 4 + cb;
        tile[i * 65 + c] = x[(b * C_ + c0 + c) * N_ + i0 + i];
      }
    }
    __syncthreads();
    {
      const int ii = t >> 2, p = t & 3;
      short8 h0, h1, l0, l1;
#pragma unroll
      for (int e = 0; e < 16; ++e) {
        const float f = tile[ii * 65 + p * 16 + e];
        const unsigned short hb = f2bf(f);
        const unsigned short lb = f2bf(f - bf2f(hb));
        if (e < 8) { h0[e] = (short)hb; l0[e] = (short)lb; }
        else       { h1[e - 8] = (short)hb; l1[e - 8] = (short)lb; }
      }
      const int base = (b * N_ + i0 + ii) * C_ + c0 + p * 16;
      *(short8*)(xthi + base) = h0;
      *(short8*)(xthi + base + 8) = h1;
      *(short8*)(xtlo + base) = l0;
      *(short8*)(xtlo + base + 8) = l1;
    }
  } else {
    const int e = (bi - 1024) * 256 + t;  // < 81920
    const float* src; unsigned short *hi, *lo; int idx;
    if (e < 8192)        { src = Wq; hi = wqh; lo = wql; idx = e; }
    else if (e < 16384)  { src = Wk; hi = wkh; lo = wkl; idx = e - 8192; }
    else                 { src = Wv; hi = wvh; lo = wvl; idx = e - 16384; }
    float f = src[idx];
    if (e < 8192) f *= LOG2E;  // log2-domain scores: fold log2(e) into Wq
    const unsigned short h = f2bf(f);
    hi[idx] = h;
    lo[idx] = f2bf(f - bf2f(h));
  }
}

// ---------------- kernel 2: fused q/k/v projection GEMM ----------------
__global__ __launch_bounds__(256) void k_proj(
    const unsigned short* __restrict__ wqh, const unsigned short* __restrict__ wql,
    const unsigned short* __restrict__ wkh, const unsigned short* __restrict__ wkl,
    const unsigned short* __restrict__ wvh, const unsigned short* __restrict__ wvl,
    const unsigned short* __restrict__ xthi, const unsigned short* __restrict__ xtlo,
    const float* __restrict__ bq, const float* __restrict__ bk,
    const float* __restrict__ bv,
    unsigned short* __restrict__ qhg, unsigned short* __restrict__ qlg,
    unsigned short* __restrict__ khg, unsigned short* __restrict__ klg,
    unsigned short* __restrict__ vg) {
  __shared__ __align__(16) char sm[33792];
  unsigned short* awh = (unsigned short*)sm;       // [64][64] W hi (swizzled)
  unsigned short* awl = awh + 4096;
  unsigned short* bxh = awl + 4096;                // [64][64] x^T hi
  unsigned short* bxl = bxh + 4096;
  float* qt = (float*)sm;                          // epilogue reuse: [64][65] f32

  const int it = blockIdx.x, ot = blockIdx.y, b = blockIdx.z;
  const int i0 = it * 64, o0 = ot * 64;
  const int t = threadIdx.x, lane = t & 63, w = t >> 6, h = lane >> 5;
  const int mb = w >> 1, nb = w & 1;
  const int srow = t >> 2, sp = t & 3;

  const int og = o0 + srow;
  const unsigned short *wh, *wl;
  if (og < 32)      { wh = wqh + og * C_;        wl = wql + og * C_; }
  else if (og < 64) { wh = wkh + (og - 32) * C_; wl = wkl + (og - 32) * C_; }
  else              { wh = wvh + (og - 64) * C_; wl = wvl + (og - 64) * C_; }
  const unsigned short* xh = xthi + (b * N_ + i0 + srow) * C_;
  const unsigned short* xl = xtlo + (b * N_ + i0 + srow) * C_;

  f32x16 acc;
#pragma unroll
  for (int e = 0; e < 16; ++e) acc[e] = 0.f;
  const int m = 32 * mb + (lane & 31);
  const int n = 32 * nb + (lane & 31);

  for (int kt = 0; kt < 4; ++kt) {
    const int cb = kt * 64 + sp * 16;
    *(short8*)&awh[swz64(srow, sp * 16)]     = *(const short8*)(wh + cb);
    *(short8*)&awh[swz64(srow, sp * 16 + 8)] = *(const short8*)(wh + cb + 8);
    *(short8*)&awl[swz64(srow, sp * 16)]     = *(const short8*)(wl + cb);
    *(short8*)&awl[swz64(srow, sp * 16 + 8)] = *(const short8*)(wl + cb + 8);
    *(short8*)&bxh[swz64(srow, sp * 16)]     = *(const short8*)(xh + cb);
    *(short8*)&bxh[swz64(srow, sp * 16 + 8)] = *(const short8*)(xh + cb + 8);
    *(short8*)&bxl[swz64(srow, sp * 16)]     = *(const short8*)(xl + cb);
    *(short8*)&bxl[swz64(srow, sp * 16 + 8)] = *(const short8*)(xl + cb + 8);
    __syncthreads();
#pragma unroll
    for (int kk = 0; kk < 4; ++kk) {
      const int kb = kk * 16 + h * 8;
      const short8 ah  = *(const short8*)&awh[swz64(m, kb)];
      const short8 al2 = *(const short8*)&awl[swz64(m, kb)];
      const short8 bh  = *(const short8*)&bxh[swz64(n, kb)];
      const short8 bl2 = *(const short8*)&bxl[swz64(n, kb)];
      acc = mfma16(ah, bh, acc);   // hi*hi
      acc = mfma16(ah, bl2, acc);  // hi*lo
      acc = mfma16(al2, bh, acc);  // lo*hi
    }
    __syncthreads();
  }

  if (ot > 0) {  // v epilogue: direct [B][C][N] bf16 store
#pragma unroll
    for (int e = 0; e < 16; ++e) {
      const int r = 32 * mb + (e & 3) + 8 * (e >> 2) + 4 * h;
      const int oc = o0 - 64 + r;
      vg[(b * C_ + oc) * N_ + i0 + n] = f2bf(acc[e] + bv[oc]);
    }
  } else {  // q/k epilogue: LDS transpose -> [B][N][32] hi/lo
#pragma unroll
    for (int e = 0; e < 16; ++e) {
      const int r = 32 * mb + (e & 3) + 8 * (e >> 2) + 4 * h;
      const float bias = (r < 32) ? bq[r] * LOG2E : bk[r - 32];
      qt[r * 65 + n] = acc[e] + bias;
    }
    __syncthreads();
    const int ii = t >> 2;
    short8 hv0, hv1, lv0, lv1;
#pragma unroll
    for (int e = 0; e < 16; ++e) {
      const float f = qt[(sp * 16 + e) * 65 + ii];
      const unsigned short hb = f2bf(f);
      const unsigned short lb = f2bf(f - bf2f(hb));
      if (e < 8) { hv0[e] = (short)hb; lv0[e] = (short)lb; }
      else       { hv1[e - 8] = (short)hb; lv1[e - 8] = (short)lb; }
    }
    if (sp < 2) {
      const int base = (b * N_ + i0 + ii) * CQK + sp * 16;
      *(short8*)(qhg + base) = hv0; *(short8*)(qhg + base + 8) = hv1;
      *(short8*)(qlg + base) = lv0; *(short8*)(qlg + base + 8) = lv1;
    } else {
      const int base = (b * N_ + i0 + ii) * CQK + sp * 16 - 32;
      *(short8*)(khg + base) = hv0; *(short8*)(khg + base + 8) = hv1;
      *(short8*)(klg + base) = lv0; *(short8*)(klg + base + 8) = lv1;
    }
  }
}

// ---------------- kernel 3: merged-wave flash, fixed-M softmax --------------
// 1024 blocks x 256 thr (4 waves), zero barriers, zero LDS. Decode:
// xs = blk&7 = b*2 + s_hi (XCD-pinned K/V/Q slice ~1.8MB L2-resident);
// gl = blk>>3: s_lo = gl&1; widx = (gl>>1)*4+w: qw = widx>>1, ch = widx&1.
// Wave = 32 q-rows x 128 channels, keys [s*1024, s*1024+1024) in 16 tiles.
// Per tile: QK (swapped, lane=q) -> exp2 (fixed M=0, log2 domain) ->
// cvt_pk + shfl_xor(32) redistribution -> PV. Epilogue: per-REGISTER-row
// 1/l via __shfl (acc reg e = q-row (e&3)+8*(e>>2)+4h, NOT lane!) then
// normalized f16 store + l. Opart: [wave 4096][slot 8][lane 64][8 f16].
__global__ __launch_bounds__(256, 4) void k_flash(
    const unsigned short* __restrict__ qhg, const unsigned short* __restrict__ qlg,
    const unsigned short* __restrict__ khg, const unsigned short* __restrict__ klg,
    const unsigned short* __restrict__ vg,
    unsigned short* __restrict__ Opart, float* __restrict__ lpart) {
  const int blk = blockIdx.x;
  const int xs = blk & 7;          // XCD-pinned (b, s_hi)
  const int b = xs >> 1;
  const int gl = blk >> 3;         // 0..127
  const int s = (xs & 1) * 2 + (gl & 1);
  const int t = threadIdx.x, lane = t & 63, w = t >> 6, h = lane >> 5;
  const int l31 = lane & 31;
  const int widx = (gl >> 1) * 4 + w;  // 0..255
  const int qw = widx >> 1, ch = widx & 1;
  const int srow = qw * 32 + l31;  // q row of this lane (QK layout)
  const int jbase = s * 1024;

  // Q fragments (persistent): B-operand for QK, lane = q
  short8 qfh[2], qfl[2];
  {
    const unsigned short* qph = qhg + (size_t)(b * N_ + srow) * CQK + h * 8;
    const unsigned short* qpl = qlg + (size_t)(b * N_ + srow) * CQK + h * 8;
#pragma unroll
    for (int kk = 0; kk < 2; ++kk) {
      qfh[kk] = *(const short8*)(qph + kk * 16);
      qfl[kk] = *(const short8*)(qpl + kk * 16);
    }
  }
  // K fragments: A-operand for QK, lane = key-row (within 32)
  const unsigned short* kph = khg + (size_t)(b * N_ + jbase + l31) * CQK + h * 8;
  const unsigned short* kpl = klg + (size_t)(b * N_ + jbase + l31) * CQK + h * 8;
  short8 kfh[2][2], kfl[2][2];
  auto loadK = [&](int tau) {
#pragma unroll
    for (int jt = 0; jt < 2; ++jt)
#pragma unroll
      for (int kk = 0; kk < 2; ++kk) {
        kfh[jt][kk] = *(const short8*)(kph + tau * 2048 + jt * 1024 + kk * 16);
        kfl[jt][kk] = *(const short8*)(kpl + tau * 2048 + jt * 1024 + kk * 16);
      }
  };
  loadK(0);
  // V pointers: B-operand for PV, lane = channel; 4 c-tiles of 32
  const unsigned short* vsr0 =
      vg + (size_t)(b * C_ + ch * 128 + l31) * N_ + jbase + h * 8;

  f32x16 acc0, acc1, acc2, acc3;
#pragma unroll
  for (int e = 0; e < 16; ++e) {
    acc0[e] = 0.f; acc1[e] = 0.f; acc2[e] = 0.f; acc3[e] = 0.f;
  }
  float l_run = 0.f;  // own half (32 j's per tile); partner-merged at end

  for (int kt = 0; kt < 16; ++kt) {
    // V loads for this tile (complete under QK+exp2)
    short8 vf0[4], vf1[4], vf2[4], vf3[4];
#pragma unroll
    for (int sl = 0; sl < 4; ++sl) {
      vf0[sl] = *(const short8*)(vsr0 + (size_t)0 * 32 * N_ + kt * 64 + sl * 16);
      vf1[sl] = *(const short8*)(vsr0 + (size_t)1 * 32 * N_ + kt * 64 + sl * 16);
      vf2[sl] = *(const short8*)(vsr0 + (size_t)2 * 32 * N_ + kt * 64 + sl * 16);
      vf3[sl] = *(const short8*)(vsr0 + (size_t)3 * 32 * N_ + kt * 64 + sl * 16);
    }
    // QK: S^T tiles, lane = q, regs = j pattern (e&3)+8*(e>>2)+4h
    f32x16 s0, s1;
#pragma unroll
    for (int e = 0; e < 16; ++e) { s0[e] = 0.f; s1[e] = 0.f; }
    __builtin_amdgcn_s_setprio(1);
#pragma unroll
    for (int kk = 0; kk < 2; ++kk) {
      s0 = mfma16(kfh[0][kk], qfh[kk], s0);
      s0 = mfma16(kfh[0][kk], qfl[kk], s0);
      s0 = mfma16(kfl[0][kk], qfh[kk], s0);
      s1 = mfma16(kfh[1][kk], qfh[kk], s1);
      s1 = mfma16(kfh[1][kk], qfl[kk], s1);
      s1 = mfma16(kfl[1][kk], qfh[kk], s1);
    }
    __builtin_amdgcn_s_setprio(0);
    if (kt + 1 < 16) loadK(kt + 1);  // prefetch next K under exp2+PV
    // ---- fixed-M softmax: P = exp2(S) (log2 domain), no max chain ----
#pragma unroll
    for (int e = 0; e < 16; ++e) s0[e] = __builtin_exp2f(s0[e]);
#pragma unroll
    for (int e = 0; e < 16; ++e) s1[e] = __builtin_exp2f(s1[e]);
    {
      float t8[8];
#pragma unroll
      for (int i2 = 0; i2 < 4; ++i2) {
        t8[i2] = (s0[4 * i2] + s0[4 * i2 + 1]) + (s0[4 * i2 + 2] + s0[4 * i2 + 3]);
        t8[4 + i2] = (s1[4 * i2] + s1[4 * i2 + 1]) + (s1[4 * i2 + 2] + s1[4 * i2 + 3]);
      }
      l_run += ((t8[0] + t8[1]) + (t8[2] + t8[3])) +
               ((t8[4] + t8[5]) + (t8[6] + t8[7]));
    }
    // ---- in-register P redistribution -> PV A-frags (verified layout) ----
    short8 pa0, pa1, pa2, pa3;
    {
      unsigned int w01 = cvtpk(s0[0], s0[1]),  w23 = cvtpk(s0[2], s0[3]);
      unsigned int w45 = cvtpk(s0[4], s0[5]),  w67 = cvtpk(s0[6], s0[7]);
      unsigned int w89 = cvtpk(s0[8], s0[9]),  wab = cvtpk(s0[10], s0[11]);
      unsigned int wcd = cvtpk(s0[12], s0[13]), wef = cvtpk(s0[14], s0[15]);
      unsigned int t01 = (unsigned)__shfl_xor((int)w01, 32);
      unsigned int t23 = (unsigned)__shfl_xor((int)w23, 32);
      unsigned int t45 = (unsigned)__shfl_xor((int)w45, 32);
      unsigned int t67 = (unsigned)__shfl_xor((int)w67, 32);
      unsigned int t89 = (unsigned)__shfl_xor((int)w89, 32);
      unsigned int tab = (unsigned)__shfl_xor((int)wab, 32);
      unsigned int tcd = (unsigned)__shfl_xor((int)wcd, 32);
      unsigned int tef = (unsigned)__shfl_xor((int)wef, 32);
      uint4v uA, uB;
      uA[0] = h ? t45 : w01;  uA[1] = h ? t67 : w23;
      uA[2] = h ? w45 : t01;  uA[3] = h ? w67 : t23;
      uB[0] = h ? tcd : w89;  uB[1] = h ? tef : wab;
      uB[2] = h ? wcd : t89;  uB[3] = h ? wef : tab;
      pa0 = __builtin_bit_cast(short8, uA);
      pa1 = __builtin_bit_cast(short8, uB);
    }
    {
      unsigned int w01 = cvtpk(s1[0], s1[1]),  w23 = cvtpk(s1[2], s1[3]);
      unsigned int w45 = cvtpk(s1[4], s1[5]),  w67 = cvtpk(s1[6], s1[7]);
      unsigned int w89 = cvtpk(s1[8], s1[9]),  wab = cvtpk(s1[10], s1[11]);
      unsigned int wcd = cvtpk(s1[12], s1[13]), wef = cvtpk(s1[14], s1[15]);
      unsigned int t01 = (unsigned)__shfl_xor((int)w01, 32);
      unsigned int t23 = (unsigned)__shfl_xor((int)w23, 32);
      unsigned int t45 = (unsigned)__shfl_xor((int)w45, 32);
      unsigned int t67 = (unsigned)__shfl_xor((int)w67, 32);
      unsigned int t89 = (unsigned)__shfl_xor((int)w89, 32);
      unsigned int tab = (unsigned)__shfl_xor((int)wab, 32);
      unsigned int tcd = (unsigned)__shfl_xor((int)wcd, 32);
      unsigned int tef = (unsigned)__shfl_xor((int)wef, 32);
      uint4v uA, uB;
      uA[0] = h ? t45 : w01;  uA[1] = h ? t67 : w23;
      uA[2] = h ? w45 : t01;  uA[3] = h ? w67 : t23;
      uB[0] = h ? tcd : w89;  uB[1] = h ? tef : wab;
      uB[2] = h ? wcd : t89;  uB[3] = h ? wef : tab;
      pa2 = __builtin_bit_cast(short8, uA);
      pa3 = __builtin_bit_cast(short8, uB);
    }
    // ---- PV: acc[ct] += P^T * V (D: lane=c, regs=q pattern) ----
    __builtin_amdgcn_s_setprio(1);
    acc0 = mfma16(pa0, vf0[0], acc0);
    acc0 = mfma16(pa1, vf0[1], acc0);
    acc0 = mfma16(pa2, vf0[2], acc0);
    acc0 = mfma16(pa3, vf0[3], acc0);
    acc1 = mfma16(pa0, vf1[0], acc1);
    acc1 = mfma16(pa1, vf1[1], acc1);
    acc1 = mfma16(pa2, vf1[2], acc1);
    acc1 = mfma16(pa3, vf1[3], acc1);
    acc2 = mfma16(pa0, vf2[0], acc2);
    acc2 = mfma16(pa1, vf2[1], acc2);
    acc2 = mfma16(pa2, vf2[2], acc2);
    acc2 = mfma16(pa3, vf2[3], acc2);
    acc3 = mfma16(pa0, vf3[0], acc3);
    acc3 = mfma16(pa1, vf3[1], acc3);
    acc3 = mfma16(pa2, vf3[2], acc3);
    acc3 = mfma16(pa3, vf3[3], acc3);
    __builtin_amdgcn_s_setprio(0);
  }

  // full-row l (both j-halves); valid for q-row = l31
  const float lfull = l_run + __shfl_xor(l_run, 32);
  if (ch == 0 && h == 0) {
    lpart[(size_t)(s * 4 + b) * 4096 + srow] = lfull;
  }
  // FIX (r10 bug): acc register e belongs to q-row (e&3)+8*(e>>2)+4h, not
  // lane. Redistribute 1/l from lane-indexed to register-row-indexed.
  const float invo = 1.0f / lfull;
  float invr[16];
#pragma unroll
  for (int e = 0; e < 16; ++e)
    invr[e] = __shfl(invo, (e & 3) + 8 * (e >> 2) + 4 * h);
  {
    const int wv = ((s * 4 + b) * 128 + qw) * 2 + ch;
    unsigned short* dst = Opart + (size_t)wv * 4096 + lane * 8;
    short8 o;
#pragma unroll
    for (int e = 0; e < 8; ++e) o[e] = f32tof16(acc0[e] * invr[e]);
    *(short8*)(dst + 0 * 512) = o;
#pragma unroll
    for (int e = 0; e < 8; ++e) o[e] = f32tof16(acc0[8 + e] * invr[8 + e]);
    *(short8*)(dst + 1 * 512) = o;
#pragma unroll
    for (int e = 0; e < 8; ++e) o[e] = f32tof16(acc1[e] * invr[e]);
    *(short8*)(dst + 2 * 512) = o;
#pragma unroll
    for (int e = 0; e < 8; ++e) o[e] = f32tof16(acc1[8 + e] * invr[8 + e]);
    *(short8*)(dst + 3 * 512) = o;
#pragma unroll
    for (int e = 0; e < 8; ++e) o[e] = f32tof16(acc2[e] * invr[e]);
    *(short8*)(dst + 4 * 512) = o;
#pragma unroll
    for (int e = 0; e < 8; ++e) o[e] = f32tof16(acc2[8 + e] * invr[8 + e]);
    *(short8*)(dst + 5 * 512) = o;
#pragma unroll
    for (int e = 0; e < 8; ++e) o[e] = f32tof16(acc3[e] * invr[e]);
    *(short8*)(dst + 6 * 512) = o;
#pragma unroll
    for (int e = 0; e < 8; ++e) o[e] = f32tof16(acc3[8 + e] * invr[8 + e]);
    *(short8*)(dst + 7 * 512) = o;
  }
}

// ---------------- kernel 4: combine 4 splits + residual ----------------
// O = sum_s (l_s / L) * Obar_s, L = sum l_s (exact under fixed M).
// Opart sub-index for (c, qg): qw = qg>>5; qi = qg&31; h = (qi>>2)&1;
// hi8 = qi>>4; eo = (qi&3)+4*((qi>>3)&1); lane = (c&31)+32h; ct = (c>>5)&3;
// ch = c>>7.
__global__ __launch_bounds__(256) void k_combine(
    const unsigned short* __restrict__ Opart, const float* __restrict__ lpart,
    const float* __restrict__ x, const float* __restrict__ gamma,
    float* __restrict__ out) {
  const int cb = blockIdx.x;
  const int b = cb & 3, qt_ = cb >> 2;
  const int q0 = qt_ * 64;
  const int t = threadIdx.x;
  const int i = t & 63, cg = t >> 6;
  const int qg = q0 + i;

  float lv[4];
#pragma unroll
  for (int s = 0; s < 4; ++s) lv[s] = lpart[(size_t)(s * 4 + b) * 4096 + qg];
  const float L = (lv[0] + lv[1]) + (lv[2] + lv[3]);
  const float giv = gamma[0] / L;
  float sc[4];
#pragma unroll
  for (int s = 0; s < 4; ++s) sc[s] = lv[s] * giv;

  const int qw = qg >> 5, qi = qg & 31;
  const int h = (qi >> 2) & 1;
  const int hi8 = qi >> 4;
  const int eo = (qi & 3) + 4 * ((qi >> 3) & 1);
#pragma unroll 4
  for (int c = cg; c < C_; c += 4) {
    const int ch = c >> 7, ct = (c >> 5) & 3, ln = (c & 31) + 32 * h;
    const size_t sub = (size_t)(ct * 2 + hi8) * 512 + ln * 8 + eo;
    float acc = 0.f;
#pragma unroll
    for (int s = 0; s < 4; ++s) {
      const size_t o =
          (size_t)(((s * 4 + b) * 128 + qw) * 2 + ch) * 4096 + sub;
      acc += sc[s] * (float)__builtin_bit_cast(_Float16, Opart[o]);
    }
    const int g = (b * C_ + c) * N_ + qg;
    out[g] = acc + x[g];
  }
}

// ---------------- launch ----------------
extern "C" void kernel_launch(void* const* d_in, const int* in_sizes, int n_in,
                              void* d_out, int out_size, void* d_ws, size_t ws_size,
                              hipStream_t stream) {
  const float* x     = (const float*)d_in[0];
  const float* Wq    = (const float*)d_in[1];
  const float* bq    = (const float*)d_in[2];
  const float* Wk    = (const float*)d_in[3];
  const float* bk    = (const float*)d_in[4];
  const float* Wv    = (const float*)d_in[5];
  const float* bv    = (const float*)d_in[6];
  const float* gamma = (const float*)d_in[7];
  float* out = (float*)d_out;
  (void)in_sizes; (void)n_in; (void)out_size; (void)ws_size;

  char* ws = (char*)d_ws;
  size_t off = 0;
  auto carve = [&](size_t bytes) -> char* {
    char* p = ws + off;
    off += (bytes + 255) & ~(size_t)255;
    return p;
  };
  unsigned short* xthi = (unsigned short*)carve((size_t)B_ * N_ * C_ * 2);
  unsigned short* xtlo = (unsigned short*)carve((size_t)B_ * N_ * C_ * 2);
  unsigned short* wqh  = (unsigned short*)carve(32 * 256 * 2);
  unsigned short* wql  = (unsigned short*)carve(32 * 256 * 2);
  unsigned short* wkh  = (unsigned short*)carve(32 * 256 * 2);
  unsigned short* wkl  = (unsigned short*)carve(32 * 256 * 2);
  unsigned short* wvh  = (unsigned short*)carve(256 * 256 * 2);
  unsigned short* wvl  = (unsigned short*)carve(256 * 256 * 2);
  unsigned short* qhg  = (unsigned short*)carve((size_t)B_ * N_ * CQK * 2);
  unsigned short* qlg  = (unsigned short*)carve((size_t)B_ * N_ * CQK * 2);
  unsigned short* khg  = (unsigned short*)carve((size_t)B_ * N_ * CQK * 2);
  unsigned short* klg  = (unsigned short*)carve((size_t)B_ * N_ * CQK * 2);
  unsigned short* vg   = (unsigned short*)carve((size_t)B_ * C_ * N_ * 2);
  unsigned short* Opart = (unsigned short*)carve((size_t)4096 * 4096 * 2);  // f16
  float* lpart = (float*)carve((size_t)16 * 4096 * 4);

  k_prep<<<1344, 256, 0, stream>>>(x, xthi, xtlo, Wq, Wk, Wv,
                                   wqh, wql, wkh, wkl, wvh, wvl);
  k_proj<<<dim3(64, 5, B_), 256, 0, stream>>>(wqh, wql, wkh, wkl, wvh, wvl,
                                              xthi, xtlo, bq, bk, bv,
                                              qhg, qlg, khg, klg, vg);
  k_flash<<<1024, 256, 0, stream>>>(qhg, qlg, khg, klg, vg, Opart, lpart);
  k_combine<<<256, 256, 0, stream>>>(Opart, lpart, x, gamma, out);
}

// Round 9
// 256.217 us; speedup vs baseline: 2.4372x; 2.4372x over previous
//
#include <hip/hip_runtime.h>

// SelfAttention (B=4, C=256, H=W=64): fused projections + merged-wave flash.
// Round 12: r11 PASSED but k_flash=537us with WRITE_SIZE 1.57GB / FETCH 0.9GB
// -> textbook scratch spill: __launch_bounds__(256,4) capped VGPR at 128 while
// the wave holds ~200 live (acc64+vf64+s32+kf32+qf16+pa16). Fix (minimal):
//  - __launch_bounds__(256,2): restore 256-VGPR budget (r9 compiled 124 this way).
//  - halve V live range: load V{ct0,1} -> PV{0,1} -> load V{ct2,3} -> PV{2,3}
//    (peak ~170 live -> targets 3 waves/SIMD).
//  - everything else unchanged from r11: fixed-M exp2 softmax, zero barriers,
//    zero LDS, split-K x4 (1024 blocks), normalized f16 partials + l, exact
//    4-way weighted combine.

#define B_ 4
#define C_ 256
#define N_ 4096
#define CQK 32
#define LOG2E 1.44269504088896340736f

typedef __attribute__((ext_vector_type(8))) short short8;
typedef __attribute__((ext_vector_type(4))) short short4v;
typedef __attribute__((ext_vector_type(4))) unsigned int uint4v;
typedef __attribute__((ext_vector_type(16))) float f32x16;
typedef __attribute__((ext_vector_type(4))) float f32x4;

__device__ __forceinline__ unsigned short f2bf(float f) {
  unsigned int u = __builtin_bit_cast(unsigned int, f);
  u = (u + 0x7fffu + ((u >> 16) & 1u)) >> 16;  // RNE
  return (unsigned short)u;
}
__device__ __forceinline__ float bf2f(unsigned short s) {
  unsigned int u = ((unsigned int)s) << 16;
  return __builtin_bit_cast(float, u);
}
__device__ __forceinline__ short f32tof16(float f) {
  const _Float16 hf = (_Float16)f;
  return __builtin_bit_cast(short, hf);
}
// pack two f32 -> two bf16 (RNE), one instruction
__device__ __forceinline__ unsigned int cvtpk(float lo, float hi) {
  unsigned int r;
  asm("v_cvt_pk_bf16_f32 %0, %1, %2" : "=v"(r) : "v"(lo), "v"(hi));
  return r;
}
__device__ __forceinline__ f32x16 mfma16(short8 a, short8 b, f32x16 c) {
  return __builtin_amdgcn_mfma_f32_32x32x16_bf16(a, b, c, 0, 0, 0);
}
// swizzled element index into bf16 LDS tiles (16B granules XORed by row)
__device__ __forceinline__ int swz64(int row, int col) {  // rows of 64 bf16
  return row * 64 + ((((col >> 3) ^ row) & 7) << 3) + (col & 7);
}

// ---------------- kernel 1: prep (x transpose+split, weight splits) ----------
__global__ __launch_bounds__(256) void k_prep(
    const float* __restrict__ x, unsigned short* __restrict__ xthi,
    unsigned short* __restrict__ xtlo,
    const float* __restrict__ Wq, const float* __restrict__ Wk,
    const float* __restrict__ Wv,
    unsigned short* __restrict__ wqh, unsigned short* __restrict__ wql,
    unsigned short* __restrict__ wkh, unsigned short* __restrict__ wkl,
    unsigned short* __restrict__ wvh, unsigned short* __restrict__ wvl) {
  __shared__ __align__(16) float tile[64 * 65];
  const int bi = blockIdx.x;
  const int t = threadIdx.x;
  if (bi < 1024) {
    const int it = bi & 63, ct = (bi >> 6) & 3, b = bi >> 8;
    const int i0 = it * 64, c0 = ct * 64;
    {
      const int i = t & 63, cb = t >> 6;
#pragma unroll
      for (int z = 0; z < 16; ++z) {
        const int c = z * 4 + cb;
        tile[i * 65 + c] = x[(b * C_ + c0 + c) * N_ + i0 + i];
      }
    }
    __syncthreads();
    {
      const int ii = t >> 2, p = t & 3;
      short8 h0, h1, l0, l1;
#pragma unroll
      for (int e = 0; e < 16; ++e) {
        const float f = tile[ii * 65 + p * 16 + e];
        const unsigned short hb = f2bf(f);
        const unsigned short lb = f2bf(f - bf2f(hb));
        if (e < 8) { h0[e] = (short)hb; l0[e] = (short)lb; }
        else       { h1[e - 8] = (short)hb; l1[e - 8] = (short)lb; }
      }
      const int base = (b * N_ + i0 + ii) * C_ + c0 + p * 16;
      *(short8*)(xthi + base) = h0;
      *(short8*)(xthi + base + 8) = h1;
      *(short8*)(xtlo + base) = l0;
      *(short8*)(xtlo + base + 8) = l1;
    }
  } else {
    const int e = (bi - 1024) * 256 + t;  // < 81920
    const float* src; unsigned short *hi, *lo; int idx;
    if (e < 8192)        { src = Wq; hi = wqh; lo = wql; idx = e; }
    else if (e < 16384)  { src = Wk; hi = wkh; lo = wkl; idx = e - 8192; }
    else                 { src = Wv; hi = wvh; lo = wvl; idx = e - 16384; }
    float f = src[idx];
    if (e < 8192) f *= LOG2E;  // log2-domain scores: fold log2(e) into Wq
    const unsigned short h = f2bf(f);
    hi[idx] = h;
    lo[idx] = f2bf(f - bf2f(h));
  }
}

// ---------------- kernel 2: fused q/k/v projection GEMM ----------------
__global__ __launch_bounds__(256) void k_proj(
    const unsigned short* __restrict__ wqh, const unsigned short* __restrict__ wql,
    const unsigned short* __restrict__ wkh, const unsigned short* __restrict__ wkl,
    const unsigned short* __restrict__ wvh, const unsigned short* __restrict__ wvl,
    const unsigned short* __restrict__ xthi, const unsigned short* __restrict__ xtlo,
    const float* __restrict__ bq, const float* __restrict__ bk,
    const float* __restrict__ bv,
    unsigned short* __restrict__ qhg, unsigned short* __restrict__ qlg,
    unsigned short* __restrict__ khg, unsigned short* __restrict__ klg,
    unsigned short* __restrict__ vg) {
  __shared__ __align__(16) char sm[33792];
  unsigned short* awh = (unsigned short*)sm;       // [64][64] W hi (swizzled)
  unsigned short* awl = awh + 4096;
  unsigned short* bxh = awl + 4096;                // [64][64] x^T hi
  unsigned short* bxl = bxh + 4096;
  float* qt = (float*)sm;                          // epilogue reuse: [64][65] f32

  const int it = blockIdx.x, ot = blockIdx.y, b = blockIdx.z;
  const int i0 = it * 64, o0 = ot * 64;
  const int t = threadIdx.x, lane = t & 63, w = t >> 6, h = lane >> 5;
  const int mb = w >> 1, nb = w & 1;
  const int srow = t >> 2, sp = t & 3;

  const int og = o0 + srow;
  const unsigned short *wh, *wl;
  if (og < 32)      { wh = wqh + og * C_;        wl = wql + og * C_; }
  else if (og < 64) { wh = wkh + (og - 32) * C_; wl = wkl + (og - 32) * C_; }
  else              { wh = wvh + (og - 64) * C_; wl = wvl + (og - 64) * C_; }
  const unsigned short* xh = xthi + (b * N_ + i0 + srow) * C_;
  const unsigned short* xl = xtlo + (b * N_ + i0 + srow) * C_;

  f32x16 acc;
#pragma unroll
  for (int e = 0; e < 16; ++e) acc[e] = 0.f;
  const int m = 32 * mb + (lane & 31);
  const int n = 32 * nb + (lane & 31);

  for (int kt = 0; kt < 4; ++kt) {
    const int cb = kt * 64 + sp * 16;
    *(short8*)&awh[swz64(srow, sp * 16)]     = *(const short8*)(wh + cb);
    *(short8*)&awh[swz64(srow, sp * 16 + 8)] = *(const short8*)(wh + cb + 8);
    *(short8*)&awl[swz64(srow, sp * 16)]     = *(const short8*)(wl + cb);
    *(short8*)&awl[swz64(srow, sp * 16 + 8)] = *(const short8*)(wl + cb + 8);
    *(short8*)&bxh[swz64(srow, sp * 16)]     = *(const short8*)(xh + cb);
    *(short8*)&bxh[swz64(srow, sp * 16 + 8)] = *(const short8*)(xh + cb + 8);
    *(short8*)&bxl[swz64(srow, sp * 16)]     = *(const short8*)(xl + cb);
    *(short8*)&bxl[swz64(srow, sp * 16 + 8)] = *(const short8*)(xl + cb + 8);
    __syncthreads();
#pragma unroll
    for (int kk = 0; kk < 4; ++kk) {
      const int kb = kk * 16 + h * 8;
      const short8 ah  = *(const short8*)&awh[swz64(m, kb)];
      const short8 al2 = *(const short8*)&awl[swz64(m, kb)];
      const short8 bh  = *(const short8*)&bxh[swz64(n, kb)];
      const short8 bl2 = *(const short8*)&bxl[swz64(n, kb)];
      acc = mfma16(ah, bh, acc);   // hi*hi
      acc = mfma16(ah, bl2, acc);  // hi*lo
      acc = mfma16(al2, bh, acc);  // lo*hi
    }
    __syncthreads();
  }

  if (ot > 0) {  // v epilogue: direct [B][C][N] bf16 store
#pragma unroll
    for (int e = 0; e < 16; ++e) {
      const int r = 32 * mb + (e & 3) + 8 * (e >> 2) + 4 * h;
      const int oc = o0 - 64 + r;
      vg[(b * C_ + oc) * N_ + i0 + n] = f2bf(acc[e] + bv[oc]);
    }
  } else {  // q/k epilogue: LDS transpose -> [B][N][32] hi/lo
#pragma unroll
    for (int e = 0; e < 16; ++e) {
      const int r = 32 * mb + (e & 3) + 8 * (e >> 2) + 4 * h;
      const float bias = (r < 32) ? bq[r] * LOG2E : bk[r - 32];
      qt[r * 65 + n] = acc[e] + bias;
    }
    __syncthreads();
    const int ii = t >> 2;
    short8 hv0, hv1, lv0, lv1;
#pragma unroll
    for (int e = 0; e < 16; ++e) {
      const float f = qt[(sp * 16 + e) * 65 + ii];
      const unsigned short hb = f2bf(f);
      const unsigned short lb = f2bf(f - bf2f(hb));
      if (e < 8) { hv0[e] = (short)hb; lv0[e] = (short)lb; }
      else       { hv1[e - 8] = (short)hb; lv1[e - 8] = (short)lb; }
    }
    if (sp < 2) {
      const int base = (b * N_ + i0 + ii) * CQK + sp * 16;
      *(short8*)(qhg + base) = hv0; *(short8*)(qhg + base + 8) = hv1;
      *(short8*)(qlg + base) = lv0; *(short8*)(qlg + base + 8) = lv1;
    } else {
      const int base = (b * N_ + i0 + ii) * CQK + sp * 16 - 32;
      *(short8*)(khg + base) = hv0; *(short8*)(khg + base + 8) = hv1;
      *(short8*)(klg + base) = lv0; *(short8*)(klg + base + 8) = lv1;
    }
  }
}

// ---------------- kernel 3: merged-wave flash, fixed-M softmax --------------
// 1024 blocks x 256 thr (4 waves), zero barriers, zero LDS. Decode:
// xs = blk&7 = b*2 + s_hi (XCD-pinned K/V/Q slice ~1.8MB L2-resident);
// gl = blk>>3: s_lo = gl&1; widx = (gl>>1)*4+w: qw = widx>>1, ch = widx&1.
// Wave = 32 q-rows x 128 channels, keys [s*1024, s*1024+1024) in 16 tiles.
// Per tile: QK (swapped, lane=q) -> exp2 (fixed M=0, log2 domain) ->
// cvt_pk + shfl_xor(32) redistribution -> PV in TWO HALVES (V{0,1} then
// V{2,3}) to halve V live range. Epilogue: per-REGISTER-row 1/l via __shfl
// then normalized f16 store + l. Opart: [wave 4096][slot 8][lane 64][8 f16].
__global__ __launch_bounds__(256, 2) void k_flash(
    const unsigned short* __restrict__ qhg, const unsigned short* __restrict__ qlg,
    const unsigned short* __restrict__ khg, const unsigned short* __restrict__ klg,
    const unsigned short* __restrict__ vg,
    unsigned short* __restrict__ Opart, float* __restrict__ lpart) {
  const int blk = blockIdx.x;
  const int xs = blk & 7;          // XCD-pinned (b, s_hi)
  const int b = xs >> 1;
  const int gl = blk >> 3;         // 0..127
  const int s = (xs & 1) * 2 + (gl & 1);
  const int t = threadIdx.x, lane = t & 63, w = t >> 6, h = lane >> 5;
  const int l31 = lane & 31;
  const int widx = (gl >> 1) * 4 + w;  // 0..255
  const int qw = widx >> 1, ch = widx & 1;
  const int srow = qw * 32 + l31;  // q row of this lane (QK layout)
  const int jbase = s * 1024;

  // Q fragments (persistent): B-operand for QK, lane = q
  short8 qfh[2], qfl[2];
  {
    const unsigned short* qph = qhg + (size_t)(b * N_ + srow) * CQK + h * 8;
    const unsigned short* qpl = qlg + (size_t)(b * N_ + srow) * CQK + h * 8;
#pragma unroll
    for (int kk = 0; kk < 2; ++kk) {
      qfh[kk] = *(const short8*)(qph + kk * 16);
      qfl[kk] = *(const short8*)(qpl + kk * 16);
    }
  }
  // K fragments: A-operand for QK, lane = key-row (within 32)
  const unsigned short* kph = khg + (size_t)(b * N_ + jbase + l31) * CQK + h * 8;
  const unsigned short* kpl = klg + (size_t)(b * N_ + jbase + l31) * CQK + h * 8;
  short8 kfh[2][2], kfl[2][2];
  auto loadK = [&](int tau) {
#pragma unroll
    for (int jt = 0; jt < 2; ++jt)
#pragma unroll
      for (int kk = 0; kk < 2; ++kk) {
        kfh[jt][kk] = *(const short8*)(kph + tau * 2048 + jt * 1024 + kk * 16);
        kfl[jt][kk] = *(const short8*)(kpl + tau * 2048 + jt * 1024 + kk * 16);
      }
  };
  loadK(0);
  // V pointers: B-operand for PV, lane = channel; 4 c-tiles of 32
  const unsigned short* vsr0 =
      vg + (size_t)(b * C_ + ch * 128 + l31) * N_ + jbase + h * 8;

  f32x16 acc0, acc1, acc2, acc3;
#pragma unroll
  for (int e = 0; e < 16; ++e) {
    acc0[e] = 0.f; acc1[e] = 0.f; acc2[e] = 0.f; acc3[e] = 0.f;
  }
  float l_run = 0.f;  // own half (32 j's per tile); partner-merged at end

  for (int kt = 0; kt < 16; ++kt) {
    // QK: S^T tiles, lane = q, regs = j pattern (e&3)+8*(e>>2)+4h
    f32x16 s0, s1;
#pragma unroll
    for (int e = 0; e < 16; ++e) { s0[e] = 0.f; s1[e] = 0.f; }
    __builtin_amdgcn_s_setprio(1);
#pragma unroll
    for (int kk = 0; kk < 2; ++kk) {
      s0 = mfma16(kfh[0][kk], qfh[kk], s0);
      s0 = mfma16(kfh[0][kk], qfl[kk], s0);
      s0 = mfma16(kfl[0][kk], qfh[kk], s0);
      s1 = mfma16(kfh[1][kk], qfh[kk], s1);
      s1 = mfma16(kfh[1][kk], qfl[kk], s1);
      s1 = mfma16(kfl[1][kk], qfh[kk], s1);
    }
    __builtin_amdgcn_s_setprio(0);
    if (kt + 1 < 16) loadK(kt + 1);  // prefetch next K under exp2+PV
    // ---- fixed-M softmax: P = exp2(S) (log2 domain), no max chain ----
#pragma unroll
    for (int e = 0; e < 16; ++e) s0[e] = __builtin_exp2f(s0[e]);
#pragma unroll
    for (int e = 0; e < 16; ++e) s1[e] = __builtin_exp2f(s1[e]);
    {
      float t8[8];
#pragma unroll
      for (int i2 = 0; i2 < 4; ++i2) {
        t8[i2] = (s0[4 * i2] + s0[4 * i2 + 1]) + (s0[4 * i2 + 2] + s0[4 * i2 + 3]);
        t8[4 + i2] = (s1[4 * i2] + s1[4 * i2 + 1]) + (s1[4 * i2 + 2] + s1[4 * i2 + 3]);
      }
      l_run += ((t8[0] + t8[1]) + (t8[2] + t8[3])) +
               ((t8[4] + t8[5]) + (t8[6] + t8[7]));
    }
    // ---- in-register P redistribution -> PV A-frags (verified layout) ----
    short8 pa0, pa1, pa2, pa3;
    {
      unsigned int w01 = cvtpk(s0[0], s0[1]),  w23 = cvtpk(s0[2], s0[3]);
      unsigned int w45 = cvtpk(s0[4], s0[5]),  w67 = cvtpk(s0[6], s0[7]);
      unsigned int w89 = cvtpk(s0[8], s0[9]),  wab = cvtpk(s0[10], s0[11]);
      unsigned int wcd = cvtpk(s0[12], s0[13]), wef = cvtpk(s0[14], s0[15]);
      unsigned int t01 = (unsigned)__shfl_xor((int)w01, 32);
      unsigned int t23 = (unsigned)__shfl_xor((int)w23, 32);
      unsigned int t45 = (unsigned)__shfl_xor((int)w45, 32);
      unsigned int t67 = (unsigned)__shfl_xor((int)w67, 32);
      unsigned int t89 = (unsigned)__shfl_xor((int)w89, 32);
      unsigned int tab = (unsigned)__shfl_xor((int)wab, 32);
      unsigned int tcd = (unsigned)__shfl_xor((int)wcd, 32);
      unsigned int tef = (unsigned)__shfl_xor((int)wef, 32);
      uint4v uA, uB;
      uA[0] = h ? t45 : w01;  uA[1] = h ? t67 : w23;
      uA[2] = h ? w45 : t01;  uA[3] = h ? w67 : t23;
      uB[0] = h ? tcd : w89;  uB[1] = h ? tef : wab;
      uB[2] = h ? wcd : t89;  uB[3] = h ? wef : tab;
      pa0 = __builtin_bit_cast(short8, uA);
      pa1 = __builtin_bit_cast(short8, uB);
    }
    {
      unsigned int w01 = cvtpk(s1[0], s1[1]),  w23 = cvtpk(s1[2], s1[3]);
      unsigned int w45 = cvtpk(s1[4], s1[5]),  w67 = cvtpk(s1[6], s1[7]);
      unsigned int w89 = cvtpk(s1[8], s1[9]),  wab = cvtpk(s1[10], s1[11]);
      unsigned int wcd = cvtpk(s1[12], s1[13]), wef = cvtpk(s1[14], s1[15]);
      unsigned int t01 = (unsigned)__shfl_xor((int)w01, 32);
      unsigned int t23 = (unsigned)__shfl_xor((int)w23, 32);
      unsigned int t45 = (unsigned)__shfl_xor((int)w45, 32);
      unsigned int t67 = (unsigned)__shfl_xor((int)w67, 32);
      unsigned int t89 = (unsigned)__shfl_xor((int)w89, 32);
      unsigned int tab = (unsigned)__shfl_xor((int)wab, 32);
      unsigned int tcd = (unsigned)__shfl_xor((int)wcd, 32);
      unsigned int tef = (unsigned)__shfl_xor((int)wef, 32);
      uint4v uA, uB;
      uA[0] = h ? t45 : w01;  uA[1] = h ? t67 : w23;
      uA[2] = h ? w45 : t01;  uA[3] = h ? w67 : t23;
      uB[0] = h ? tcd : w89;  uB[1] = h ? tef : wab;
      uB[2] = h ? wcd : t89;  uB[3] = h ? wef : tab;
      pa2 = __builtin_bit_cast(short8, uA);
      pa3 = __builtin_bit_cast(short8, uB);
    }
    // ---- PV in two halves (halved V live range) ----
    {
      short8 vfA[4], vfB[4];
#pragma unroll
      for (int sl = 0; sl < 4; ++sl) {
        vfA[sl] = *(const short8*)(vsr0 + (size_t)0 * 32 * N_ + kt * 64 + sl * 16);
        vfB[sl] = *(const short8*)(vsr0 + (size_t)1 * 32 * N_ + kt * 64 + sl * 16);
      }
      __builtin_amdgcn_s_setprio(1);
      acc0 = mfma16(pa0, vfA[0], acc0);
      acc0 = mfma16(pa1, vfA[1], acc0);
      acc0 = mfma16(pa2, vfA[2], acc0);
      acc0 = mfma16(pa3, vfA[3], acc0);
      acc1 = mfma16(pa0, vfB[0], acc1);
      acc1 = mfma16(pa1, vfB[1], acc1);
      acc1 = mfma16(pa2, vfB[2], acc1);
      acc1 = mfma16(pa3, vfB[3], acc1);
      __builtin_amdgcn_s_setprio(0);
    }
    {
      short8 vfA[4], vfB[4];
#pragma unroll
      for (int sl = 0; sl < 4; ++sl) {
        vfA[sl] = *(const short8*)(vsr0 + (size_t)2 * 32 * N_ + kt * 64 + sl * 16);
        vfB[sl] = *(const short8*)(vsr0 + (size_t)3 * 32 * N_ + kt * 64 + sl * 16);
      }
      __builtin_amdgcn_s_setprio(1);
      acc2 = mfma16(pa0, vfA[0], acc2);
      acc2 = mfma16(pa1, vfA[1], acc2);
      acc2 = mfma16(pa2, vfA[2], acc2);
      acc2 = mfma16(pa3, vfA[3], acc2);
      acc3 = mfma16(pa0, vfB[0], acc3);
      acc3 = mfma16(pa1, vfB[1], acc3);
      acc3 = mfma16(pa2, vfB[2], acc3);
      acc3 = mfma16(pa3, vfB[3], acc3);
      __builtin_amdgcn_s_setprio(0);
    }
  }

  // full-row l (both j-halves); valid for q-row = l31
  const float lfull = l_run + __shfl_xor(l_run, 32);
  if (ch == 0 && h == 0) {
    lpart[(size_t)(s * 4 + b) * 4096 + srow] = lfull;
  }
  // acc register e belongs to q-row (e&3)+8*(e>>2)+4h, not lane:
  // redistribute 1/l from lane-indexed to register-row-indexed.
  const float invo = 1.0f / lfull;
  float invr[16];
#pragma unroll
  for (int e = 0; e < 16; ++e)
    invr[e] = __shfl(invo, (e & 3) + 8 * (e >> 2) + 4 * h);
  {
    const int wv = ((s * 4 + b) * 128 + qw) * 2 + ch;
    unsigned short* dst = Opart + (size_t)wv * 4096 + lane * 8;
    short8 o;
#pragma unroll
    for (int e = 0; e < 8; ++e) o[e] = f32tof16(acc0[e] * invr[e]);
    *(short8*)(dst + 0 * 512) = o;
#pragma unroll
    for (int e = 0; e < 8; ++e) o[e] = f32tof16(acc0[8 + e] * invr[8 + e]);
    *(short8*)(dst + 1 * 512) = o;
#pragma unroll
    for (int e = 0; e < 8; ++e) o[e] = f32tof16(acc1[e] * invr[e]);
    *(short8*)(dst + 2 * 512) = o;
#pragma unroll
    for (int e = 0; e < 8; ++e) o[e] = f32tof16(acc1[8 + e] * invr[8 + e]);
    *(short8*)(dst + 3 * 512) = o;
#pragma unroll
    for (int e = 0; e < 8; ++e) o[e] = f32tof16(acc2[e] * invr[e]);
    *(short8*)(dst + 4 * 512) = o;
#pragma unroll
    for (int e = 0; e < 8; ++e) o[e] = f32tof16(acc2[8 + e] * invr[8 + e]);
    *(short8*)(dst + 5 * 512) = o;
#pragma unroll
    for (int e = 0; e < 8; ++e) o[e] = f32tof16(acc3[e] * invr[e]);
    *(short8*)(dst + 6 * 512) = o;
#pragma unroll
    for (int e = 0; e < 8; ++e) o[e] = f32tof16(acc3[8 + e] * invr[8 + e]);
    *(short8*)(dst + 7 * 512) = o;
  }
}

// ---------------- kernel 4: combine 4 splits + residual ----------------
// O = sum_s (l_s / L) * Obar_s, L = sum l_s (exact under fixed M).
// Opart sub-index for (c, qg): qw = qg>>5; qi = qg&31; h = (qi>>2)&1;
// hi8 = qi>>4; eo = (qi&3)+4*((qi>>3)&1); lane = (c&31)+32h; ct = (c>>5)&3;
// ch = c>>7.
__global__ __launch_bounds__(256) void k_combine(
    const unsigned short* __restrict__ Opart, const float* __restrict__ lpart,
    const float* __restrict__ x, const float* __restrict__ gamma,
    float* __restrict__ out) {
  const int cb = blockIdx.x;
  const int b = cb & 3, qt_ = cb >> 2;
  const int q0 = qt_ * 64;
  const int t = threadIdx.x;
  const int i = t & 63, cg = t >> 6;
  const int qg = q0 + i;

  float lv[4];
#pragma unroll
  for (int s = 0; s < 4; ++s) lv[s] = lpart[(size_t)(s * 4 + b) * 4096 + qg];
  const float L = (lv[0] + lv[1]) + (lv[2] + lv[3]);
  const float giv = gamma[0] / L;
  float sc[4];
#pragma unroll
  for (int s = 0; s < 4; ++s) sc[s] = lv[s] * giv;

  const int qw = qg >> 5, qi = qg & 31;
  const int h = (qi >> 2) & 1;
  const int hi8 = qi >> 4;
  const int eo = (qi & 3) + 4 * ((qi >> 3) & 1);
#pragma unroll 4
  for (int c = cg; c < C_; c += 4) {
    const int ch = c >> 7, ct = (c >> 5) & 3, ln = (c & 31) + 32 * h;
    const size_t sub = (size_t)(ct * 2 + hi8) * 512 + ln * 8 + eo;
    float acc = 0.f;
#pragma unroll
    for (int s = 0; s < 4; ++s) {
      const size_t o =
          (size_t)(((s * 4 + b) * 128 + qw) * 2 + ch) * 4096 + sub;
      acc += sc[s] * (float)__builtin_bit_cast(_Float16, Opart[o]);
    }
    const int g = (b * C_ + c) * N_ + qg;
    out[g] = acc + x[g];
  }
}

// ---------------- launch ----------------
extern "C" void kernel_launch(void* const* d_in, const int* in_sizes, int n_in,
                              void* d_out, int out_size, void* d_ws, size_t ws_size,
                              hipStream_t stream) {
  const float* x     = (const float*)d_in[0];
  const float* Wq    = (const float*)d_in[1];
  const float* bq    = (const float*)d_in[2];
  const float* Wk    = (const float*)d_in[3];
  const float* bk    = (const float*)d_in[4];
  const float* Wv    = (const float*)d_in[5];
  const float* bv    = (const float*)d_in[6];
  const float* gamma = (const float*)d_in[7];
  float* out = (float*)d_out;
  (void)in_sizes; (void)n_in; (void)out_size; (void)ws_size;

  char* ws = (char*)d_ws;
  size_t off = 0;
  auto carve = [&](size_t bytes) -> char* {
    char* p = ws + off;
    off += (bytes + 255) & ~(size_t)255;
    return p;
  };
  unsigned short* xthi = (unsigned short*)carve((size_t)B_ * N_ * C_ * 2);
  unsigned short* xtlo = (unsigned short*)carve((size_t)B_ * N_ * C_ * 2);
  unsigned short* wqh  = (unsigned short*)carve(32 * 256 * 2);
  unsigned short* wql  = (unsigned short*)carve(32 * 256 * 2);
  unsigned short* wkh  = (unsigned short*)carve(32 * 256 * 2);
  unsigned short* wkl  = (unsigned short*)carve(32 * 256 * 2);
  unsigned short* wvh  = (unsigned short*)carve(256 * 256 * 2);
  unsigned short* wvl  = (unsigned short*)carve(256 * 256 * 2);
  unsigned short* qhg  = (unsigned short*)carve((size_t)B_ * N_ * CQK * 2);
  unsigned short* qlg  = (unsigned short*)carve((size_t)B_ * N_ * CQK * 2);
  unsigned short* khg  = (unsigned short*)carve((size_t)B_ * N_ * CQK * 2);
  unsigned short* klg  = (unsigned short*)carve((size_t)B_ * N_ * CQK * 2);
  unsigned short* vg   = (unsigned short*)carve((size_t)B_ * C_ * N_ * 2);
  unsigned short* Opart = (unsigned short*)carve((size_t)4096 * 4096 * 2);  // f16
  float* lpart = (float*)carve((size_t)16 * 4096 * 4);

  k_prep<<<1344, 256, 0, stream>>>(x, xthi, xtlo, Wq, Wk, Wv,
                                   wqh, wql, wkh, wkl, wvh, wvl);
  k_proj<<<dim3(64, 5, B_), 256, 0, stream>>>(wqh, wql, wkh, wkl, wvh, wvl,
                                              xthi, xtlo, bq, bk, bv,
                                              qhg, qlg, khg, klg, vg);
  k_flash<<<1024, 256, 0, stream>>>(qhg, qlg, khg, klg, vg, Opart, lpart);
  k_combine<<<256, 256, 0, stream>>>(Opart, lpart, x, gamma, out);
}

// Round 10
// 188.092 us; speedup vs baseline: 3.3199x; 1.3622x over previous
//
#include <hip/hip_runtime.h>

// SelfAttention (B=4, C=256, H=W=64): fused projections + merged-wave flash.
// Round 13: r12 (162us, no spill) still pinned at MfmaUtil 15 / VALU 23 / HBM 3%.
// Diagnosis: fragment loads (lane=row, stride 64B..8KB) are scatter-gathers ->
// ~32 L2 requests per instruction, ~50M requests total ~= 93us at the L2's
// request rate; queueing -> 162us. This round:
//  - FRAGMENT-PACKED K/V: k_proj writes K,V in MFMA fragment order
//    ([b][tile][frag][lane][8]) so every k_flash load is base+lane*8 ->
//    contiguous 1KB wave-loads, 16 full 64B lines, sequential streams.
//    Pure address remap (math bit-identical).
//  - raw s_barrier per tile phase-locks the 4 waves: waves share K (x4) and
//    V (x2 per ch) streams -> laggards hit L1 (24KB/tile < 32KB), deduping
//    requests to ~10M.
// Everything else = r12: fixed-M exp2 softmax, split-K x4 (1024 blocks x 4
// waves), zero LDS, normalized f16 partials + l, exact 4-way combine.

#define B_ 4
#define C_ 256
#define N_ 4096
#define CQK 32
#define LOG2E 1.44269504088896340736f

typedef __attribute__((ext_vector_type(8))) short short8;
typedef __attribute__((ext_vector_type(4))) short short4v;
typedef __attribute__((ext_vector_type(4))) unsigned int uint4v;
typedef __attribute__((ext_vector_type(16))) float f32x16;
typedef __attribute__((ext_vector_type(4))) float f32x4;

__device__ __forceinline__ unsigned short f2bf(float f) {
  unsigned int u = __builtin_bit_cast(unsigned int, f);
  u = (u + 0x7fffu + ((u >> 16) & 1u)) >> 16;  // RNE
  return (unsigned short)u;
}
__device__ __forceinline__ float bf2f(unsigned short s) {
  unsigned int u = ((unsigned int)s) << 16;
  return __builtin_bit_cast(float, u);
}
__device__ __forceinline__ short f32tof16(float f) {
  const _Float16 hf = (_Float16)f;
  return __builtin_bit_cast(short, hf);
}
// pack two f32 -> two bf16 (RNE), one instruction
__device__ __forceinline__ unsigned int cvtpk(float lo, float hi) {
  unsigned int r;
  asm("v_cvt_pk_bf16_f32 %0, %1, %2" : "=v"(r) : "v"(lo), "v"(hi));
  return r;
}
__device__ __forceinline__ f32x16 mfma16(short8 a, short8 b, f32x16 c) {
  return __builtin_amdgcn_mfma_f32_32x32x16_bf16(a, b, c, 0, 0, 0);
}
// swizzled element index into bf16 LDS tiles (16B granules XORed by row)
__device__ __forceinline__ int swz64(int row, int col) {  // rows of 64 bf16
  return row * 64 + ((((col >> 3) ^ row) & 7) << 3) + (col & 7);
}

// ---------------- kernel 1: prep (x transpose+split, weight splits) ----------
__global__ __launch_bounds__(256) void k_prep(
    const float* __restrict__ x, unsigned short* __restrict__ xthi,
    unsigned short* __restrict__ xtlo,
    const float* __restrict__ Wq, const float* __restrict__ Wk,
    const float* __restrict__ Wv,
    unsigned short* __restrict__ wqh, unsigned short* __restrict__ wql,
    unsigned short* __restrict__ wkh, unsigned short* __restrict__ wkl,
    unsigned short* __restrict__ wvh, unsigned short* __restrict__ wvl) {
  __shared__ __align__(16) float tile[64 * 65];
  const int bi = blockIdx.x;
  const int t = threadIdx.x;
  if (bi < 1024) {
    const int it = bi & 63, ct = (bi >> 6) & 3, b = bi >> 8;
    const int i0 = it * 64, c0 = ct * 64;
    {
      const int i = t & 63, cb = t >> 6;
#pragma unroll
      for (int z = 0; z < 16; ++z) {
        const int c = z * 4 + cb;
        tile[i * 65 + c] = x[(b * C_ + c0 + c) * N_ + i0 + i];
      }
    }
    __syncthreads();
    {
      const int ii = t >> 2, p = t & 3;
      short8 h0, h1, l0, l1;
#pragma unroll
      for (int e = 0; e < 16; ++e) {
        const float f = tile[ii * 65 + p * 16 + e];
        const unsigned short hb = f2bf(f);
        const unsigned short lb = f2bf(f - bf2f(hb));
        if (e < 8) { h0[e] = (short)hb; l0[e] = (short)lb; }
        else       { h1[e - 8] = (short)hb; l1[e - 8] = (short)lb; }
      }
      const int base = (b * N_ + i0 + ii) * C_ + c0 + p * 16;
      *(short8*)(xthi + base) = h0;
      *(short8*)(xthi + base + 8) = h1;
      *(short8*)(xtlo + base) = l0;
      *(short8*)(xtlo + base + 8) = l1;
    }
  } else {
    const int e = (bi - 1024) * 256 + t;  // < 81920
    const float* src; unsigned short *hi, *lo; int idx;
    if (e < 8192)        { src = Wq; hi = wqh; lo = wql; idx = e; }
    else if (e < 16384)  { src = Wk; hi = wkh; lo = wkl; idx = e - 8192; }
    else                 { src = Wv; hi = wvh; lo = wvl; idx = e - 16384; }
    float f = src[idx];
    if (e < 8192) f *= LOG2E;  // log2-domain scores: fold log2(e) into Wq
    const unsigned short h = f2bf(f);
    hi[idx] = h;
    lo[idx] = f2bf(f - bf2f(h));
  }
}

// ---------------- kernel 2: fused q/k/v projection GEMM ----------------
// q written [B][N][32] hi/lo (unchanged). K and V written FRAGMENT-PACKED:
// kfr[((b*128 + j32t)*2 + kk)*64 + (jl + 32*h)]*8  holds K[j32t*32+jl][kk*16+h*8+..]
// vfr[(b*64+jt)*16384 + ct*2048 + sl*512 + (cl+32*hh)*8 + e8]
//    holds V[ct*32+cl][jt*64 + sl*16 + hh*8 + e8]
__global__ __launch_bounds__(256) void k_proj(
    const unsigned short* __restrict__ wqh, const unsigned short* __restrict__ wql,
    const unsigned short* __restrict__ wkh, const unsigned short* __restrict__ wkl,
    const unsigned short* __restrict__ wvh, const unsigned short* __restrict__ wvl,
    const unsigned short* __restrict__ xthi, const unsigned short* __restrict__ xtlo,
    const float* __restrict__ bq, const float* __restrict__ bk,
    const float* __restrict__ bv,
    unsigned short* __restrict__ qhg, unsigned short* __restrict__ qlg,
    unsigned short* __restrict__ kfrh, unsigned short* __restrict__ kfrl,
    unsigned short* __restrict__ vfr) {
  __shared__ __align__(16) char sm[33792];
  unsigned short* awh = (unsigned short*)sm;       // [64][64] W hi (swizzled)
  unsigned short* awl = awh + 4096;
  unsigned short* bxh = awl + 4096;                // [64][64] x^T hi
  unsigned short* bxl = bxh + 4096;
  float* qt = (float*)sm;                          // epilogue reuse: [64][65] f32

  const int it = blockIdx.x, ot = blockIdx.y, b = blockIdx.z;
  const int i0 = it * 64, o0 = ot * 64;
  const int t = threadIdx.x, lane = t & 63, w = t >> 6, h = lane >> 5;
  const int mb = w >> 1, nb = w & 1;
  const int srow = t >> 2, sp = t & 3;

  const int og = o0 + srow;
  const unsigned short *wh, *wl;
  if (og < 32)      { wh = wqh + og * C_;        wl = wql + og * C_; }
  else if (og < 64) { wh = wkh + (og - 32) * C_; wl = wkl + (og - 32) * C_; }
  else              { wh = wvh + (og - 64) * C_; wl = wvl + (og - 64) * C_; }
  const unsigned short* xh = xthi + (b * N_ + i0 + srow) * C_;
  const unsigned short* xl = xtlo + (b * N_ + i0 + srow) * C_;

  f32x16 acc;
#pragma unroll
  for (int e = 0; e < 16; ++e) acc[e] = 0.f;
  const int m = 32 * mb + (lane & 31);
  const int n = 32 * nb + (lane & 31);

  for (int kt = 0; kt < 4; ++kt) {
    const int cb = kt * 64 + sp * 16;
    *(short8*)&awh[swz64(srow, sp * 16)]     = *(const short8*)(wh + cb);
    *(short8*)&awh[swz64(srow, sp * 16 + 8)] = *(const short8*)(wh + cb + 8);
    *(short8*)&awl[swz64(srow, sp * 16)]     = *(const short8*)(wl + cb);
    *(short8*)&awl[swz64(srow, sp * 16 + 8)] = *(const short8*)(wl + cb + 8);
    *(short8*)&bxh[swz64(srow, sp * 16)]     = *(const short8*)(xh + cb);
    *(short8*)&bxh[swz64(srow, sp * 16 + 8)] = *(const short8*)(xh + cb + 8);
    *(short8*)&bxl[swz64(srow, sp * 16)]     = *(const short8*)(xl + cb);
    *(short8*)&bxl[swz64(srow, sp * 16 + 8)] = *(const short8*)(xl + cb + 8);
    __syncthreads();
#pragma unroll
    for (int kk = 0; kk < 4; ++kk) {
      const int kb = kk * 16 + h * 8;
      const short8 ah  = *(const short8*)&awh[swz64(m, kb)];
      const short8 al2 = *(const short8*)&awl[swz64(m, kb)];
      const short8 bh  = *(const short8*)&bxh[swz64(n, kb)];
      const short8 bl2 = *(const short8*)&bxl[swz64(n, kb)];
      acc = mfma16(ah, bh, acc);   // hi*hi
      acc = mfma16(ah, bl2, acc);  // hi*lo
      acc = mfma16(al2, bh, acc);  // lo*hi
    }
    __syncthreads();
  }

  if (ot > 0) {  // v epilogue: fragment-packed bf16 scatter store
    // thread owns (oc = o0-64+32*mb+rr, j = i0+n); it == jt, n == jl
    const int vbase = (b * 64 + it) * 16384 + (2 * (ot - 1) + mb) * 2048 +
                      (n >> 4) * 512 + 256 * ((n >> 3) & 1) + (n & 7);
#pragma unroll
    for (int e = 0; e < 16; ++e) {
      const int rr = (e & 3) + 8 * (e >> 2) + 4 * h;
      const int oc = o0 - 64 + 32 * mb + rr;
      vfr[vbase + rr * 8] = f2bf(acc[e] + bv[oc]);
    }
  } else {  // q/k epilogue: LDS transpose -> q [B][N][32]; K fragment-packed
#pragma unroll
    for (int e = 0; e < 16; ++e) {
      const int r = 32 * mb + (e & 3) + 8 * (e >> 2) + 4 * h;
      const float bias = (r < 32) ? bq[r] * LOG2E : bk[r - 32];
      qt[r * 65 + n] = acc[e] + bias;
    }
    __syncthreads();
    const int ii = t >> 2;
    short8 hv0, hv1, lv0, lv1;
#pragma unroll
    for (int e = 0; e < 16; ++e) {
      const float f = qt[(sp * 16 + e) * 65 + ii];
      const unsigned short hb = f2bf(f);
      const unsigned short lb = f2bf(f - bf2f(hb));
      if (e < 8) { hv0[e] = (short)hb; lv0[e] = (short)lb; }
      else       { hv1[e - 8] = (short)hb; lv1[e - 8] = (short)lb; }
    }
    if (sp < 2) {
      const int base = (b * N_ + i0 + ii) * CQK + sp * 16;
      *(short8*)(qhg + base) = hv0; *(short8*)(qhg + base + 8) = hv1;
      *(short8*)(qlg + base) = lv0; *(short8*)(qlg + base + 8) = lv1;
    } else {
      // key = i0+ii; hv0 = cqk[kk*16..+8] (h=0), hv1 = cqk[kk*16+8..] (h=1)
      const int key = i0 + ii;
      const int j32t = key >> 5, jl = key & 31;
      const int kk = sp - 2;
      const size_t kb2 = ((size_t)(b * 128 + j32t) * 2 + kk) * 512;
      *(short8*)(kfrh + kb2 + jl * 8) = hv0;
      *(short8*)(kfrh + kb2 + (jl + 32) * 8) = hv1;
      *(short8*)(kfrl + kb2 + jl * 8) = lv0;
      *(short8*)(kfrl + kb2 + (jl + 32) * 8) = lv1;
    }
  }
}

// ---------------- kernel 3: merged-wave flash, fixed-M, packed operands -----
// 1024 blocks x 256 thr (4 waves). xs = blk&7 = b*2+s_hi (XCD-pinned);
// gl = blk>>3: s = (xs&1)*2 + (gl&1); widx = (gl>>1)*4+w: qw=widx>>1, ch=widx&1.
// Wave = 32 q-rows x 128 channels, keys [s*1024,+1024) in 16 tiles of 64.
// All K/V loads are contiguous 1KB wave-loads from fragment-packed buffers.
// One raw s_barrier per tile phase-locks the 4 waves (K shared x4, V x2 ->
// L1 dedup). Fixed-M exp2 softmax; in-register P redistribution; normalized
// f16 partials + l. Opart: [wave 4096][slot 8][lane 64][8 f16].
__global__ __launch_bounds__(256, 2) void k_flash(
    const unsigned short* __restrict__ qhg, const unsigned short* __restrict__ qlg,
    const unsigned short* __restrict__ kfrh, const unsigned short* __restrict__ kfrl,
    const unsigned short* __restrict__ vfr,
    unsigned short* __restrict__ Opart, float* __restrict__ lpart) {
  const int blk = blockIdx.x;
  const int xs = blk & 7;          // XCD-pinned (b, s_hi)
  const int b = xs >> 1;
  const int gl = blk >> 3;         // 0..127
  const int s = (xs & 1) * 2 + (gl & 1);
  const int t = threadIdx.x, lane = t & 63, w = t >> 6, h = lane >> 5;
  const int l31 = lane & 31;
  const int widx = (gl >> 1) * 4 + w;  // 0..255
  const int qw = widx >> 1, ch = widx & 1;
  const int srow = qw * 32 + l31;  // q row of this lane (QK layout)

  // Q fragments (persistent): B-operand for QK, lane = q
  short8 qfh[2], qfl[2];
  {
    const unsigned short* qph = qhg + (size_t)(b * N_ + srow) * CQK + h * 8;
    const unsigned short* qpl = qlg + (size_t)(b * N_ + srow) * CQK + h * 8;
#pragma unroll
    for (int kk = 0; kk < 2; ++kk) {
      qfh[kk] = *(const short8*)(qph + kk * 16);
      qfl[kk] = *(const short8*)(qpl + kk * 16);
    }
  }
  // K fragments: packed blocks of 512 shorts, local j32t = tau*2+jt
  const unsigned short* kbh = kfrh + (size_t)(b * 128 + s * 32) * 1024 + lane * 8;
  const unsigned short* kbl = kfrl + (size_t)(b * 128 + s * 32) * 1024 + lane * 8;
  short8 kfh[2][2], kfl[2][2];
  auto loadK = [&](int tau) {
#pragma unroll
    for (int jt = 0; jt < 2; ++jt)
#pragma unroll
      for (int kk = 0; kk < 2; ++kk) {
        const int off = ((tau * 2 + jt) * 2 + kk) * 512;
        kfh[jt][kk] = *(const short8*)(kbh + off);
        kfl[jt][kk] = *(const short8*)(kbl + off);
      }
  };
  loadK(0);
  // V fragments: packed; per (tile kt, ctl, sl) a contiguous 1KB wave-load
  const unsigned short* vbase =
      vfr + (size_t)(b * 64 + s * 16) * 16384 + (ch * 4) * 2048 + lane * 8;

  f32x16 acc0, acc1, acc2, acc3;
#pragma unroll
  for (int e = 0; e < 16; ++e) {
    acc0[e] = 0.f; acc1[e] = 0.f; acc2[e] = 0.f; acc3[e] = 0.f;
  }
  float l_run = 0.f;  // own half (32 j's per tile); partner-merged at end

  for (int kt = 0; kt < 16; ++kt) {
    __builtin_amdgcn_s_barrier();  // phase-lock 4 waves -> L1 stream dedup
    // QK: S^T tiles, lane = q, regs = j pattern (e&3)+8*(e>>2)+4h
    f32x16 s0, s1;
#pragma unroll
    for (int e = 0; e < 16; ++e) { s0[e] = 0.f; s1[e] = 0.f; }
    __builtin_amdgcn_s_setprio(1);
#pragma unroll
    for (int kk = 0; kk < 2; ++kk) {
      s0 = mfma16(kfh[0][kk], qfh[kk], s0);
      s0 = mfma16(kfh[0][kk], qfl[kk], s0);
      s0 = mfma16(kfl[0][kk], qfh[kk], s0);
      s1 = mfma16(kfh[1][kk], qfh[kk], s1);
      s1 = mfma16(kfh[1][kk], qfl[kk], s1);
      s1 = mfma16(kfl[1][kk], qfh[kk], s1);
    }
    __builtin_amdgcn_s_setprio(0);
    if (kt + 1 < 16) loadK(kt + 1);  // prefetch next K under exp2+PV
    // ---- fixed-M softmax: P = exp2(S) (log2 domain), no max chain ----
#pragma unroll
    for (int e = 0; e < 16; ++e) s0[e] = __builtin_exp2f(s0[e]);
#pragma unroll
    for (int e = 0; e < 16; ++e) s1[e] = __builtin_exp2f(s1[e]);
    {
      float t8[8];
#pragma unroll
      for (int i2 = 0; i2 < 4; ++i2) {
        t8[i2] = (s0[4 * i2] + s0[4 * i2 + 1]) + (s0[4 * i2 + 2] + s0[4 * i2 + 3]);
        t8[4 + i2] = (s1[4 * i2] + s1[4 * i2 + 1]) + (s1[4 * i2 + 2] + s1[4 * i2 + 3]);
      }
      l_run += ((t8[0] + t8[1]) + (t8[2] + t8[3])) +
               ((t8[4] + t8[5]) + (t8[6] + t8[7]));
    }
    // ---- in-register P redistribution -> PV A-frags (verified layout) ----
    short8 pa0, pa1, pa2, pa3;
    {
      unsigned int w01 = cvtpk(s0[0], s0[1]),  w23 = cvtpk(s0[2], s0[3]);
      unsigned int w45 = cvtpk(s0[4], s0[5]),  w67 = cvtpk(s0[6], s0[7]);
      unsigned int w89 = cvtpk(s0[8], s0[9]),  wab = cvtpk(s0[10], s0[11]);
      unsigned int wcd = cvtpk(s0[12], s0[13]), wef = cvtpk(s0[14], s0[15]);
      unsigned int t01 = (unsigned)__shfl_xor((int)w01, 32);
      unsigned int t23 = (unsigned)__shfl_xor((int)w23, 32);
      unsigned int t45 = (unsigned)__shfl_xor((int)w45, 32);
      unsigned int t67 = (unsigned)__shfl_xor((int)w67, 32);
      unsigned int t89 = (unsigned)__shfl_xor((int)w89, 32);
      unsigned int tab = (unsigned)__shfl_xor((int)wab, 32);
      unsigned int tcd = (unsigned)__shfl_xor((int)wcd, 32);
      unsigned int tef = (unsigned)__shfl_xor((int)wef, 32);
      uint4v uA, uB;
      uA[0] = h ? t45 : w01;  uA[1] = h ? t67 : w23;
      uA[2] = h ? w45 : t01;  uA[3] = h ? w67 : t23;
      uB[0] = h ? tcd : w89;  uB[1] = h ? tef : wab;
      uB[2] = h ? wcd : t89;  uB[3] = h ? wef : tab;
      pa0 = __builtin_bit_cast(short8, uA);
      pa1 = __builtin_bit_cast(short8, uB);
    }
    {
      unsigned int w01 = cvtpk(s1[0], s1[1]),  w23 = cvtpk(s1[2], s1[3]);
      unsigned int w45 = cvtpk(s1[4], s1[5]),  w67 = cvtpk(s1[6], s1[7]);
      unsigned int w89 = cvtpk(s1[8], s1[9]),  wab = cvtpk(s1[10], s1[11]);
      unsigned int wcd = cvtpk(s1[12], s1[13]), wef = cvtpk(s1[14], s1[15]);
      unsigned int t01 = (unsigned)__shfl_xor((int)w01, 32);
      unsigned int t23 = (unsigned)__shfl_xor((int)w23, 32);
      unsigned int t45 = (unsigned)__shfl_xor((int)w45, 32);
      unsigned int t67 = (unsigned)__shfl_xor((int)w67, 32);
      unsigned int t89 = (unsigned)__shfl_xor((int)w89, 32);
      unsigned int tab = (unsigned)__shfl_xor((int)wab, 32);
      unsigned int tcd = (unsigned)__shfl_xor((int)wcd, 32);
      unsigned int tef = (unsigned)__shfl_xor((int)wef, 32);
      uint4v uA, uB;
      uA[0] = h ? t45 : w01;  uA[1] = h ? t67 : w23;
      uA[2] = h ? w45 : t01;  uA[3] = h ? w67 : t23;
      uB[0] = h ? tcd : w89;  uB[1] = h ? tef : wab;
      uB[2] = h ? wcd : t89;  uB[3] = h ? wef : tab;
      pa2 = __builtin_bit_cast(short8, uA);
      pa3 = __builtin_bit_cast(short8, uB);
    }
    // ---- PV in two halves (V loads contiguous, halved live range) ----
    {
      short8 vfA[4], vfB[4];
#pragma unroll
      for (int sl = 0; sl < 4; ++sl) {
        vfA[sl] = *(const short8*)(vbase + kt * 16384 + 0 * 2048 + sl * 512);
        vfB[sl] = *(const short8*)(vbase + kt * 16384 + 1 * 2048 + sl * 512);
      }
      __builtin_amdgcn_s_setprio(1);
      acc0 = mfma16(pa0, vfA[0], acc0);
      acc0 = mfma16(pa1, vfA[1], acc0);
      acc0 = mfma16(pa2, vfA[2], acc0);
      acc0 = mfma16(pa3, vfA[3], acc0);
      acc1 = mfma16(pa0, vfB[0], acc1);
      acc1 = mfma16(pa1, vfB[1], acc1);
      acc1 = mfma16(pa2, vfB[2], acc1);
      acc1 = mfma16(pa3, vfB[3], acc1);
      __builtin_amdgcn_s_setprio(0);
    }
    {
      short8 vfA[4], vfB[4];
#pragma unroll
      for (int sl = 0; sl < 4; ++sl) {
        vfA[sl] = *(const short8*)(vbase + kt * 16384 + 2 * 2048 + sl * 512);
        vfB[sl] = *(const short8*)(vbase + kt * 16384 + 3 * 2048 + sl * 512);
      }
      __builtin_amdgcn_s_setprio(1);
      acc2 = mfma16(pa0, vfA[0], acc2);
      acc2 = mfma16(pa1, vfA[1], acc2);
      acc2 = mfma16(pa2, vfA[2], acc2);
      acc2 = mfma16(pa3, vfA[3], acc2);
      acc3 = mfma16(pa0, vfB[0], acc3);
      acc3 = mfma16(pa1, vfB[1], acc3);
      acc3 = mfma16(pa2, vfB[2], acc3);
      acc3 = mfma16(pa3, vfB[3], acc3);
      __builtin_amdgcn_s_setprio(0);
    }
  }

  // full-row l (both j-halves); valid for q-row = l31
  const float lfull = l_run + __shfl_xor(l_run, 32);
  if (ch == 0 && h == 0) {
    lpart[(size_t)(s * 4 + b) * 4096 + srow] = lfull;
  }
  // acc register e belongs to q-row (e&3)+8*(e>>2)+4h, not lane:
  // redistribute 1/l from lane-indexed to register-row-indexed.
  const float invo = 1.0f / lfull;
  float invr[16];
#pragma unroll
  for (int e = 0; e < 16; ++e)
    invr[e] = __shfl(invo, (e & 3) + 8 * (e >> 2) + 4 * h);
  {
    const int wv = ((s * 4 + b) * 128 + qw) * 2 + ch;
    unsigned short* dst = Opart + (size_t)wv * 4096 + lane * 8;
    short8 o;
#pragma unroll
    for (int e = 0; e < 8; ++e) o[e] = f32tof16(acc0[e] * invr[e]);
    *(short8*)(dst + 0 * 512) = o;
#pragma unroll
    for (int e = 0; e < 8; ++e) o[e] = f32tof16(acc0[8 + e] * invr[8 + e]);
    *(short8*)(dst + 1 * 512) = o;
#pragma unroll
    for (int e = 0; e < 8; ++e) o[e] = f32tof16(acc1[e] * invr[e]);
    *(short8*)(dst + 2 * 512) = o;
#pragma unroll
    for (int e = 0; e < 8; ++e) o[e] = f32tof16(acc1[8 + e] * invr[8 + e]);
    *(short8*)(dst + 3 * 512) = o;
#pragma unroll
    for (int e = 0; e < 8; ++e) o[e] = f32tof16(acc2[e] * invr[e]);
    *(short8*)(dst + 4 * 512) = o;
#pragma unroll
    for (int e = 0; e < 8; ++e) o[e] = f32tof16(acc2[8 + e] * invr[8 + e]);
    *(short8*)(dst + 5 * 512) = o;
#pragma unroll
    for (int e = 0; e < 8; ++e) o[e] = f32tof16(acc3[e] * invr[e]);
    *(short8*)(dst + 6 * 512) = o;
#pragma unroll
    for (int e = 0; e < 8; ++e) o[e] = f32tof16(acc3[8 + e] * invr[8 + e]);
    *(short8*)(dst + 7 * 512) = o;
  }
}

// ---------------- kernel 4: combine 4 splits + residual ----------------
// O = sum_s (l_s / L) * Obar_s, L = sum l_s (exact under fixed M).
// Opart sub-index for (c, qg): qw = qg>>5; qi = qg&31; h = (qi>>2)&1;
// hi8 = qi>>4; eo = (qi&3)+4*((qi>>3)&1); lane = (c&31)+32h; ct = (c>>5)&3;
// ch = c>>7.
__global__ __launch_bounds__(256) void k_combine(
    const unsigned short* __restrict__ Opart, const float* __restrict__ lpart,
    const float* __restrict__ x, const float* __restrict__ gamma,
    float* __restrict__ out) {
  const int cb = blockIdx.x;
  const int b = cb & 3, qt_ = cb >> 2;
  const int q0 = qt_ * 64;
  const int t = threadIdx.x;
  const int i = t & 63, cg = t >> 6;
  const int qg = q0 + i;

  float lv[4];
#pragma unroll
  for (int s = 0; s < 4; ++s) lv[s] = lpart[(size_t)(s * 4 + b) * 4096 + qg];
  const float L = (lv[0] + lv[1]) + (lv[2] + lv[3]);
  const float giv = gamma[0] / L;
  float sc[4];
#pragma unroll
  for (int s = 0; s < 4; ++s) sc[s] = lv[s] * giv;

  const int qw = qg >> 5, qi = qg & 31;
  const int h = (qi >> 2) & 1;
  const int hi8 = qi >> 4;
  const int eo = (qi & 3) + 4 * ((qi >> 3) & 1);
#pragma unroll 4
  for (int c = cg; c < C_; c += 4) {
    const int ch = c >> 7, ct = (c >> 5) & 3, ln = (c & 31) + 32 * h;
    const size_t sub = (size_t)(ct * 2 + hi8) * 512 + ln * 8 + eo;
    float acc = 0.f;
#pragma unroll
    for (int s = 0; s < 4; ++s) {
      const size_t o =
          (size_t)(((s * 4 + b) * 128 + qw) * 2 + ch) * 4096 + sub;
      acc += sc[s] * (float)__builtin_bit_cast(_Float16, Opart[o]);
    }
    const int g = (b * C_ + c) * N_ + qg;
    out[g] = acc + x[g];
  }
}

// ---------------- launch ----------------
extern "C" void kernel_launch(void* const* d_in, const int* in_sizes, int n_in,
                              void* d_out, int out_size, void* d_ws, size_t ws_size,
                              hipStream_t stream) {
  const float* x     = (const float*)d_in[0];
  const float* Wq    = (const float*)d_in[1];
  const float* bq    = (const float*)d_in[2];
  const float* Wk    = (const float*)d_in[3];
  const float* bk    = (const float*)d_in[4];
  const float* Wv    = (const float*)d_in[5];
  const float* bv    = (const float*)d_in[6];
  const float* gamma = (const float*)d_in[7];
  float* out = (float*)d_out;
  (void)in_sizes; (void)n_in; (void)out_size; (void)ws_size;

  char* ws = (char*)d_ws;
  size_t off = 0;
  auto carve = [&](size_t bytes) -> char* {
    char* p = ws + off;
    off += (bytes + 255) & ~(size_t)255;
    return p;
  };
  unsigned short* xthi = (unsigned short*)carve((size_t)B_ * N_ * C_ * 2);
  unsigned short* xtlo = (unsigned short*)carve((size_t)B_ * N_ * C_ * 2);
  unsigned short* wqh  = (unsigned short*)carve(32 * 256 * 2);
  unsigned short* wql  = (unsigned short*)carve(32 * 256 * 2);
  unsigned short* wkh  = (unsigned short*)carve(32 * 256 * 2);
  unsigned short* wkl  = (unsigned short*)carve(32 * 256 * 2);
  unsigned short* wvh  = (unsigned short*)carve(256 * 256 * 2);
  unsigned short* wvl  = (unsigned short*)carve(256 * 256 * 2);
  unsigned short* qhg  = (unsigned short*)carve((size_t)B_ * N_ * CQK * 2);
  unsigned short* qlg  = (unsigned short*)carve((size_t)B_ * N_ * CQK * 2);
  unsigned short* kfrh = (unsigned short*)carve((size_t)B_ * N_ * CQK * 2);
  unsigned short* kfrl = (unsigned short*)carve((size_t)B_ * N_ * CQK * 2);
  unsigned short* vfr  = (unsigned short*)carve((size_t)B_ * C_ * N_ * 2);
  unsigned short* Opart = (unsigned short*)carve((size_t)4096 * 4096 * 2);  // f16
  float* lpart = (float*)carve((size_t)16 * 4096 * 4);

  k_prep<<<1344, 256, 0, stream>>>(x, xthi, xtlo, Wq, Wk, Wv,
                                   wqh, wql, wkh, wkl, wvh, wvl);
  k_proj<<<dim3(64, 5, B_), 256, 0, stream>>>(wqh, wql, wkh, wkl, wvh, wvl,
                                              xthi, xtlo, bq, bk, bv,
                                              qhg, qlg, kfrh, kfrl, vfr);
  k_flash<<<1024, 256, 0, stream>>>(qhg, qlg, kfrh, kfrl, vfr, Opart, lpart);
  k_combine<<<256, 256, 0, stream>>>(Opart, lpart, x, gamma, out);
}